// Round 1
// baseline (2897.937 us; speedup 1.0000x reference)
//
#include <hip/hip_runtime.h>

#define N_NODES 50000
#define N_EDGES 800000

// ---------------------------------------------------------------------------
// GEMM: Y[N x M] = (RELU_IN ? relu(X) : X)[N x 128] @ W[128 x M] (+ bias)
// Block: 64 rows x M cols, 512 threads. W staged fully in LDS (K=128 fixed).
// X tile staged in LDS with stride 136 (pad +8 floats) -> x scalar reads are
// 2-way bank aliased (free per m136), W float4 reads ~2-way.
// ---------------------------------------------------------------------------
template <int M, bool RELU_IN, bool BIAS>
__global__ __launch_bounds__(512) void gemm_k(const float* __restrict__ X,
                                              const float* __restrict__ W,
                                              const float* __restrict__ bias,
                                              float* __restrict__ Y) {
    constexpr int K = 128;
    constexpr int ROWS = 64;
    constexpr int XSTR = 136;  // padded stride in floats (div by 4 for float4)

    __shared__ float wl[K * M];
    __shared__ float xl[ROWS * XSTR];

    const int tid = threadIdx.x;
    const int row0 = blockIdx.x * ROWS;

    // ---- stage W (K*M floats) via float4, all 512 threads ----
    {
        const float4* w4 = reinterpret_cast<const float4*>(W);
        float4* wl4 = reinterpret_cast<float4*>(wl);
        constexpr int TOT4 = K * M / 4;
        #pragma unroll
        for (int i = tid; i < TOT4; i += 512) wl4[i] = w4[i];
    }

    // ---- stage X tile (64 rows x 128) via float4, fused ReLU ----
    {
        const float4* x4 = reinterpret_cast<const float4*>(X);
        #pragma unroll
        for (int i = tid; i < ROWS * 32; i += 512) {
            const int r = i >> 5, c = i & 31;
            const int gr = row0 + r;
            float4 v = {0.f, 0.f, 0.f, 0.f};
            if (gr < N_NODES) v = x4[(size_t)gr * 32 + c];
            if (RELU_IN) {
                v.x = fmaxf(v.x, 0.f);
                v.y = fmaxf(v.y, 0.f);
                v.z = fmaxf(v.z, 0.f);
                v.w = fmaxf(v.w, 0.f);
            }
            reinterpret_cast<float4*>(&xl[r * XSTR])[c] = v;
        }
    }
    __syncthreads();

    // thread tile: TR rows x 8 cols
    constexpr int TPRG = M / 8;        // threads per row-group (cols covered)
    constexpr int NRG = 512 / TPRG;    // row-groups per block
    constexpr int TR = ROWS / NRG;     // rows per thread (2 for M=128, 1 for M=64)
    const int rg = tid / TPRG;
    const int c0 = (tid % TPRG) * 8;

    float acc[TR][8];
    #pragma unroll
    for (int t = 0; t < TR; ++t)
        #pragma unroll
        for (int j = 0; j < 8; ++j) acc[t][j] = 0.f;

    #pragma unroll 8
    for (int k = 0; k < K; ++k) {
        const float4 wa = *reinterpret_cast<const float4*>(&wl[k * M + c0]);
        const float4 wb = *reinterpret_cast<const float4*>(&wl[k * M + c0 + 4]);
        #pragma unroll
        for (int t = 0; t < TR; ++t) {
            const float xv = xl[(rg * TR + t) * XSTR + k];
            acc[t][0] = fmaf(xv, wa.x, acc[t][0]);
            acc[t][1] = fmaf(xv, wa.y, acc[t][1]);
            acc[t][2] = fmaf(xv, wa.z, acc[t][2]);
            acc[t][3] = fmaf(xv, wa.w, acc[t][3]);
            acc[t][4] = fmaf(xv, wb.x, acc[t][4]);
            acc[t][5] = fmaf(xv, wb.y, acc[t][5]);
            acc[t][6] = fmaf(xv, wb.z, acc[t][6]);
            acc[t][7] = fmaf(xv, wb.w, acc[t][7]);
        }
    }

    #pragma unroll
    for (int t = 0; t < TR; ++t) {
        const int gr = row0 + rg * TR + t;
        if (gr >= N_NODES) continue;
        float* yp = &Y[(size_t)gr * M + c0];
        float4 o0 = {acc[t][0], acc[t][1], acc[t][2], acc[t][3]};
        float4 o1 = {acc[t][4], acc[t][5], acc[t][6], acc[t][7]};
        if (BIAS) {
            const float4 ba = *reinterpret_cast<const float4*>(&bias[c0]);
            const float4 bb = *reinterpret_cast<const float4*>(&bias[c0 + 4]);
            o0.x += ba.x; o0.y += ba.y; o0.z += ba.z; o0.w += ba.w;
            o1.x += bb.x; o1.y += bb.y; o1.z += bb.z; o1.w += bb.w;
        }
        *reinterpret_cast<float4*>(yp) = o0;
        *reinterpret_cast<float4*>(yp + 4) = o1;
    }
}

// ---------------------------------------------------------------------------
// Scatter-add: A[dst[e]][:] += S[src[e]][:] over all edges.
// One thread per (edge, float4-chunk): coalesced float4 gather of S (cache-
// resident: 25.6 MB), 4 device-scope fp32 atomicAdds into A.
// ---------------------------------------------------------------------------
__global__ __launch_bounds__(256) void scatter_k(const float* __restrict__ S,
                                                 const int* __restrict__ dst_i,
                                                 const int* __restrict__ src_i,
                                                 float* __restrict__ A) {
    const long total = (long)N_EDGES * 32;  // 32 float4 chunks per edge row
    const float4* S4 = reinterpret_cast<const float4*>(S);
    const long stride = (long)gridDim.x * blockDim.x;
    for (long i = (long)blockIdx.x * blockDim.x + threadIdx.x; i < total; i += stride) {
        const int e = (int)(i >> 5);
        const int c = (int)(i & 31);
        const int s = src_i[e];
        const int d = dst_i[e];
        const float4 v = S4[(size_t)s * 32 + c];
        float* p = &A[(size_t)d * 128 + (size_t)c * 4];
        atomicAdd(p + 0, v.x);
        atomicAdd(p + 1, v.y);
        atomicAdd(p + 2, v.z);
        atomicAdd(p + 3, v.w);
    }
}

extern "C" void kernel_launch(void* const* d_in, const int* in_sizes, int n_in,
                              void* d_out, int out_size, void* d_ws, size_t ws_size,
                              hipStream_t stream) {
    const int* edge = (const int*)d_in[0];   // [2][E] row-major: row0=dst, row1=src
    const float* feat = (const float*)d_in[1];
    const float* W0 = (const float*)d_in[2];
    const float* W1 = (const float*)d_in[3];
    const float* Wout = (const float*)d_in[4];
    const float* bout = (const float*)d_in[5];
    float* out = (float*)d_out;

    const int* dst_i = edge;            // segment ids (edge_index[0])
    const int* src_i = edge + N_EDGES;  // gather ids  (edge_index[1])

    float* buf0 = (float*)d_ws;                       // support  [N x 128]
    float* buf1 = buf0 + (size_t)N_NODES * 128;       // agg      [N x 128]
    const size_t agg_bytes = (size_t)N_NODES * 128 * sizeof(float);

    const int gemm_blocks = (N_NODES + 63) / 64;  // 782

    // layer 1: support = feat @ W0 ; agg = A @ support
    gemm_k<128, false, false><<<gemm_blocks, 512, 0, stream>>>(feat, W0, nullptr, buf0);
    hipMemsetAsync(buf1, 0, agg_bytes, stream);
    scatter_k<<<8192, 256, 0, stream>>>(buf0, dst_i, src_i, buf1);

    // layer 2: support2 = relu(agg) @ W1 ; agg2 = A @ support2
    gemm_k<128, true, false><<<gemm_blocks, 512, 0, stream>>>(buf1, W1, nullptr, buf0);
    hipMemsetAsync(buf1, 0, agg_bytes, stream);
    scatter_k<<<8192, 256, 0, stream>>>(buf0, dst_i, src_i, buf1);

    // head: out = relu(agg2) @ W_out + b_out
    gemm_k<64, true, true><<<gemm_blocks, 512, 0, stream>>>(buf1, Wout, bout, out);
}

// Round 5
// 406.035 us; speedup vs baseline: 7.1372x; 7.1372x over previous
//
#include <hip/hip_runtime.h>

#define N_NODES 50000
#define N_EDGES 800000
#define SCAN_TILE 2048
#define SCAN_NBLK ((N_NODES + SCAN_TILE - 1) / SCAN_TILE)  // 25

// ---------------------------------------------------------------------------
// GEMM: Y[N x M] = (RELU_IN ? relu(X) : X)[N x 128] @ W[128 x M] (+ bias)
// Block: 64 rows x M cols, 512 threads. W fully LDS-resident (K=128 fixed).
// ---------------------------------------------------------------------------
template <int M, bool RELU_IN, bool BIAS>
__global__ __launch_bounds__(512) void gemm_k(const float* __restrict__ X,
                                              const float* __restrict__ W,
                                              const float* __restrict__ bias,
                                              float* __restrict__ Y) {
    constexpr int K = 128;
    constexpr int ROWS = 64;
    constexpr int XSTR = 136;

    __shared__ float wl[K * M];
    __shared__ float xl[ROWS * XSTR];

    const int tid = threadIdx.x;
    const int row0 = blockIdx.x * ROWS;

    {
        const float4* w4 = reinterpret_cast<const float4*>(W);
        float4* wl4 = reinterpret_cast<float4*>(wl);
        constexpr int TOT4 = K * M / 4;
        #pragma unroll
        for (int i = tid; i < TOT4; i += 512) wl4[i] = w4[i];
    }
    {
        const float4* x4 = reinterpret_cast<const float4*>(X);
        #pragma unroll
        for (int i = tid; i < ROWS * 32; i += 512) {
            const int r = i >> 5, c = i & 31;
            const int gr = row0 + r;
            float4 v = {0.f, 0.f, 0.f, 0.f};
            if (gr < N_NODES) v = x4[(size_t)gr * 32 + c];
            if (RELU_IN) {
                v.x = fmaxf(v.x, 0.f);
                v.y = fmaxf(v.y, 0.f);
                v.z = fmaxf(v.z, 0.f);
                v.w = fmaxf(v.w, 0.f);
            }
            reinterpret_cast<float4*>(&xl[r * XSTR])[c] = v;
        }
    }
    __syncthreads();

    constexpr int TPRG = M / 8;
    constexpr int NRG = 512 / TPRG;
    constexpr int TR = ROWS / NRG;
    const int rg = tid / TPRG;
    const int c0 = (tid % TPRG) * 8;

    float acc[TR][8];
    #pragma unroll
    for (int t = 0; t < TR; ++t)
        #pragma unroll
        for (int j = 0; j < 8; ++j) acc[t][j] = 0.f;

    #pragma unroll 8
    for (int k = 0; k < K; ++k) {
        const float4 wa = *reinterpret_cast<const float4*>(&wl[k * M + c0]);
        const float4 wb = *reinterpret_cast<const float4*>(&wl[k * M + c0 + 4]);
        #pragma unroll
        for (int t = 0; t < TR; ++t) {
            const float xv = xl[(rg * TR + t) * XSTR + k];
            acc[t][0] = fmaf(xv, wa.x, acc[t][0]);
            acc[t][1] = fmaf(xv, wa.y, acc[t][1]);
            acc[t][2] = fmaf(xv, wa.z, acc[t][2]);
            acc[t][3] = fmaf(xv, wa.w, acc[t][3]);
            acc[t][4] = fmaf(xv, wb.x, acc[t][4]);
            acc[t][5] = fmaf(xv, wb.y, acc[t][5]);
            acc[t][6] = fmaf(xv, wb.z, acc[t][6]);
            acc[t][7] = fmaf(xv, wb.w, acc[t][7]);
        }
    }

    #pragma unroll
    for (int t = 0; t < TR; ++t) {
        const int gr = row0 + rg * TR + t;
        if (gr >= N_NODES) continue;
        float* yp = &Y[(size_t)gr * M + c0];
        float4 o0 = {acc[t][0], acc[t][1], acc[t][2], acc[t][3]};
        float4 o1 = {acc[t][4], acc[t][5], acc[t][6], acc[t][7]};
        if (BIAS) {
            const float4 ba = *reinterpret_cast<const float4*>(&bias[c0]);
            const float4 bb = *reinterpret_cast<const float4*>(&bias[c0 + 4]);
            o0.x += ba.x; o0.y += ba.y; o0.z += ba.z; o0.w += ba.w;
            o1.x += bb.x; o1.y += bb.y; o1.z += bb.z; o1.w += bb.w;
        }
        *reinterpret_cast<float4*>(yp) = o0;
        *reinterpret_cast<float4*>(yp + 4) = o1;
    }
}

// ---------------------------------------------------------------------------
// CSR build: histogram -> exclusive scan (Blelloch, 2-level) -> bucket fill
// ---------------------------------------------------------------------------
__global__ __launch_bounds__(256) void hist_k(const int* __restrict__ dst_i,
                                              int* __restrict__ cnt) {
    const int stride = gridDim.x * blockDim.x;
    for (int e = blockIdx.x * blockDim.x + threadIdx.x; e < N_EDGES; e += stride)
        atomicAdd(&cnt[dst_i[e]], 1);
}

__global__ __launch_bounds__(1024) void scan1_k(const int* __restrict__ cnt,
                                                int* __restrict__ excl,
                                                int* __restrict__ bsum) {
    __shared__ int buf[SCAN_TILE];
    const int t = threadIdx.x;
    const int base = blockIdx.x * SCAN_TILE;
    buf[t] = (base + t < N_NODES) ? cnt[base + t] : 0;
    buf[t + 1024] = (base + t + 1024 < N_NODES) ? cnt[base + t + 1024] : 0;

    // upsweep
    for (int d = 1; d < SCAN_TILE; d <<= 1) {
        __syncthreads();
        const int idx = (t + 1) * d * 2 - 1;
        if (idx < SCAN_TILE) buf[idx] += buf[idx - d];
    }
    __syncthreads();
    if (t == 0) {
        bsum[blockIdx.x] = buf[SCAN_TILE - 1];
        buf[SCAN_TILE - 1] = 0;
    }
    // downsweep
    for (int d = SCAN_TILE / 2; d >= 1; d >>= 1) {
        __syncthreads();
        const int idx = (t + 1) * d * 2 - 1;
        if (idx < SCAN_TILE) {
            const int tmp = buf[idx - d];
            buf[idx - d] = buf[idx];
            buf[idx] += tmp;
        }
    }
    __syncthreads();
    if (base + t < N_NODES) excl[base + t] = buf[t];
    if (base + t + 1024 < N_NODES) excl[base + t + 1024] = buf[t + 1024];
}

__global__ void scan2_k(int* __restrict__ bsum) {
    if (threadIdx.x == 0 && blockIdx.x == 0) {
        int acc = 0;
        for (int b = 0; b < SCAN_NBLK; ++b) {
            const int v = bsum[b];
            bsum[b] = acc;
            acc += v;
        }
    }
}

__global__ __launch_bounds__(256) void scan3_k(int* __restrict__ row_start,
                                               const int* __restrict__ bsum) {
    const int stride = gridDim.x * blockDim.x;
    for (int i = blockIdx.x * blockDim.x + threadIdx.x; i < N_NODES; i += stride)
        row_start[i] += bsum[i / SCAN_TILE];
    if (blockIdx.x == 0 && threadIdx.x == 0) row_start[N_NODES] = N_EDGES;
}

__global__ __launch_bounds__(256) void fill_k(const int* __restrict__ dst_i,
                                              const int* __restrict__ src_i,
                                              int* __restrict__ cursor,
                                              int* __restrict__ csr_src) {
    const int stride = gridDim.x * blockDim.x;
    for (int e = blockIdx.x * blockDim.x + threadIdx.x; e < N_EDGES; e += stride) {
        const int p = atomicAdd(&cursor[dst_i[e]], 1);
        csr_src[p] = src_i[e];
    }
}

// ---------------------------------------------------------------------------
// Gather-aggregate: one wave per dst node. A[n][:] = sum_{j in csr[n]} S[j][:]
// lane owns a float2 column slice; each edge = one coalesced 512B row read.
// 4 independent accumulators hide L2/L3 gather latency (avg degree 16).
// ---------------------------------------------------------------------------
__global__ __launch_bounds__(256) void agg_k(const float* __restrict__ S,
                                             const int* __restrict__ row_start,
                                             const int* __restrict__ csr_src,
                                             float* __restrict__ A) {
    const int wave = threadIdx.x >> 6;
    const int lane = threadIdx.x & 63;
    const int n = blockIdx.x * 4 + wave;
    if (n >= N_NODES) return;
    const int beg = row_start[n];
    const int end = row_start[n + 1];
    const float2* S2 = reinterpret_cast<const float2*>(S);

    float2 a0 = {0.f, 0.f}, a1 = {0.f, 0.f}, a2 = {0.f, 0.f}, a3 = {0.f, 0.f};
    int j = beg;
    for (; j + 3 < end; j += 4) {
        const int s0 = csr_src[j];
        const int s1 = csr_src[j + 1];
        const int s2 = csr_src[j + 2];
        const int s3 = csr_src[j + 3];
        const float2 v0 = S2[(size_t)s0 * 64 + lane];
        const float2 v1 = S2[(size_t)s1 * 64 + lane];
        const float2 v2 = S2[(size_t)s2 * 64 + lane];
        const float2 v3 = S2[(size_t)s3 * 64 + lane];
        a0.x += v0.x; a0.y += v0.y;
        a1.x += v1.x; a1.y += v1.y;
        a2.x += v2.x; a2.y += v2.y;
        a3.x += v3.x; a3.y += v3.y;
    }
    for (; j < end; ++j) {
        const int s0 = csr_src[j];
        const float2 v0 = S2[(size_t)s0 * 64 + lane];
        a0.x += v0.x; a0.y += v0.y;
    }
    a0.x += a1.x + a2.x + a3.x;
    a0.y += a1.y + a2.y + a3.y;
    reinterpret_cast<float2*>(A)[(size_t)n * 64 + lane] = a0;
}

// ---------------------------------------------------------------------------
// Fallback (ws too small): atomic scatter
// ---------------------------------------------------------------------------
__global__ __launch_bounds__(256) void scatter_k(const float* __restrict__ S,
                                                 const int* __restrict__ dst_i,
                                                 const int* __restrict__ src_i,
                                                 float* __restrict__ A) {
    const long total = (long)N_EDGES * 32;
    const float4* S4 = reinterpret_cast<const float4*>(S);
    const long stride = (long)gridDim.x * blockDim.x;
    for (long i = (long)blockIdx.x * blockDim.x + threadIdx.x; i < total; i += stride) {
        const int e = (int)(i >> 5);
        const int c = (int)(i & 31);
        const int s = src_i[e];
        const int d = dst_i[e];
        const float4 v = S4[(size_t)s * 32 + c];
        float* p = &A[(size_t)d * 128 + (size_t)c * 4];
        atomicAdd(p + 0, v.x);
        atomicAdd(p + 1, v.y);
        atomicAdd(p + 2, v.z);
        atomicAdd(p + 3, v.w);
    }
}

extern "C" void kernel_launch(void* const* d_in, const int* in_sizes, int n_in,
                              void* d_out, int out_size, void* d_ws, size_t ws_size,
                              hipStream_t stream) {
    const int* edge = (const int*)d_in[0];   // [2][E]: row0=dst (segment ids), row1=src (gather ids)
    const float* feat = (const float*)d_in[1];
    const float* W0 = (const float*)d_in[2];
    const float* W1 = (const float*)d_in[3];
    const float* Wout = (const float*)d_in[4];
    const float* bout = (const float*)d_in[5];
    float* out = (float*)d_out;

    const int* dst_i = edge;
    const int* src_i = edge + N_EDGES;

    const size_t feat_elems = (size_t)N_NODES * 128;
    float* buf0 = (float*)d_ws;                 // support [N x 128]
    float* buf1 = buf0 + feat_elems;            // agg     [N x 128]

    // CSR region after the two float buffers
    char* p = (char*)(buf1 + feat_elems);
    int* row_start = (int*)p;                   // N+1 ints (scan output)
    p += (N_NODES + 1) * sizeof(int);
    int* cursor = (int*)p;                      // N ints (histogram, then fill cursor)
    p += N_NODES * sizeof(int);
    int* bsum = (int*)p;                        // SCAN_NBLK ints
    p += 32 * sizeof(int);
    int* csr_src = (int*)p;                     // E ints
    p += (size_t)N_EDGES * sizeof(int);
    const size_t needed = (size_t)((char*)p - (char*)d_ws);

    const int gemm_blocks = (N_NODES + 63) / 64;  // 782
    const int agg_blocks = (N_NODES + 3) / 4;     // 12500

    if (ws_size >= needed) {
        // ---- build CSR once (shared by both layers) ----
        hipMemsetAsync(cursor, 0, N_NODES * sizeof(int), stream);
        hist_k<<<1024, 256, 0, stream>>>(dst_i, cursor);
        scan1_k<<<SCAN_NBLK, 1024, 0, stream>>>(cursor, row_start, bsum);
        scan2_k<<<1, 64, 0, stream>>>(bsum);
        scan3_k<<<128, 256, 0, stream>>>(row_start, bsum);
        hipMemcpyAsync(cursor, row_start, N_NODES * sizeof(int),
                       hipMemcpyDeviceToDevice, stream);
        fill_k<<<1024, 256, 0, stream>>>(dst_i, src_i, cursor, csr_src);

        // ---- layer 1 ----
        gemm_k<128, false, false><<<gemm_blocks, 512, 0, stream>>>(feat, W0, nullptr, buf0);
        agg_k<<<agg_blocks, 256, 0, stream>>>(buf0, row_start, csr_src, buf1);
        // ---- layer 2 ----
        gemm_k<128, true, false><<<gemm_blocks, 512, 0, stream>>>(buf1, W1, nullptr, buf0);
        agg_k<<<agg_blocks, 256, 0, stream>>>(buf0, row_start, csr_src, buf1);
        // ---- head ----
        gemm_k<64, true, true><<<gemm_blocks, 512, 0, stream>>>(buf1, Wout, bout, out);
    } else {
        // fallback: atomic path
        const size_t agg_bytes = feat_elems * sizeof(float);
        gemm_k<128, false, false><<<gemm_blocks, 512, 0, stream>>>(feat, W0, nullptr, buf0);
        hipMemsetAsync(buf1, 0, agg_bytes, stream);
        scatter_k<<<8192, 256, 0, stream>>>(buf0, dst_i, src_i, buf1);
        gemm_k<128, true, false><<<gemm_blocks, 512, 0, stream>>>(buf1, W1, nullptr, buf0);
        hipMemsetAsync(buf1, 0, agg_bytes, stream);
        scatter_k<<<8192, 256, 0, stream>>>(buf0, dst_i, src_i, buf1);
        gemm_k<64, true, true><<<gemm_blocks, 512, 0, stream>>>(buf1, Wout, bout, out);
    }
}

// Round 11
// 379.004 us; speedup vs baseline: 7.6462x; 1.0713x over previous
//
#include <hip/hip_runtime.h>

#define N_NODES 50000
#define N_EDGES 800000
#define SCAN_TILE 2048
#define SCAN_NBLK ((N_NODES + SCAN_TILE - 1) / SCAN_TILE)  // 25

// ---------------------------------------------------------------------------
// GEMM: Y[N x M] = (RELU_IN ? relu(X) : X)[N x 128] @ W[128 x M] (+ bias)
// Block: 64 rows x M cols, 512 threads.
// W staged in two K-halves (32KB max) -> LDS 66KB -> 2 blocks/CU.
// Column split c_lo/c_hi at 16B lane stride -> LDS reads <=2-way (free).
// ---------------------------------------------------------------------------
template <int M, bool RELU_IN, bool BIAS>
__global__ __launch_bounds__(512) void gemm_k(const float* __restrict__ X,
                                              const float* __restrict__ W,
                                              const float* __restrict__ bias,
                                              float* __restrict__ Y) {
    constexpr int K = 128;
    constexpr int KH = 64;          // K-half staged per pass
    constexpr int ROWS = 64;
    constexpr int XSTR = 136;

    __shared__ float wl[KH * M];    // 32KB for M=128, 16KB for M=64
    __shared__ float xl[ROWS * XSTR];

    const int tid = threadIdx.x;
    const int row0 = blockIdx.x * ROWS;

    // ---- stage X tile (64 rows x 128) via float4, fused ReLU ----
    {
        const float4* x4 = reinterpret_cast<const float4*>(X);
        #pragma unroll
        for (int i = tid; i < ROWS * 32; i += 512) {
            const int r = i >> 5, c = i & 31;
            const int gr = row0 + r;
            float4 v = {0.f, 0.f, 0.f, 0.f};
            if (gr < N_NODES) v = x4[(size_t)gr * 32 + c];
            if (RELU_IN) {
                v.x = fmaxf(v.x, 0.f);
                v.y = fmaxf(v.y, 0.f);
                v.z = fmaxf(v.z, 0.f);
                v.w = fmaxf(v.w, 0.f);
            }
            reinterpret_cast<float4*>(&xl[r * XSTR])[c] = v;
        }
    }

    constexpr int TPRG = M / 8;        // threads covering the col dim
    constexpr int NRG = 512 / TPRG;    // row-groups per block
    constexpr int TR = ROWS / NRG;     // rows per thread
    const int rg = tid / TPRG;
    const int cq = tid % TPRG;
    const int c_lo = cq * 4;
    const int c_hi = M / 2 + cq * 4;

    float acc[TR][8];
    #pragma unroll
    for (int t = 0; t < TR; ++t)
        #pragma unroll
        for (int j = 0; j < 8; ++j) acc[t][j] = 0.f;

    #pragma unroll
    for (int h = 0; h < K / KH; ++h) {
        // stage W rows [h*KH, h*KH+KH) -- consecutive float4s, conflict-free
        {
            const float4* w4 = reinterpret_cast<const float4*>(W + h * KH * M);
            float4* wl4 = reinterpret_cast<float4*>(wl);
            constexpr int TOT4 = KH * M / 4;
            #pragma unroll
            for (int i = tid; i < TOT4; i += 512) wl4[i] = w4[i];
        }
        __syncthreads();

        #pragma unroll 8
        for (int k = 0; k < KH; ++k) {
            const float4 wa = *reinterpret_cast<const float4*>(&wl[k * M + c_lo]);
            const float4 wb = *reinterpret_cast<const float4*>(&wl[k * M + c_hi]);
            const int gk = h * KH + k;
            #pragma unroll
            for (int t = 0; t < TR; ++t) {
                const float xv = xl[(rg * TR + t) * XSTR + gk];
                acc[t][0] = fmaf(xv, wa.x, acc[t][0]);
                acc[t][1] = fmaf(xv, wa.y, acc[t][1]);
                acc[t][2] = fmaf(xv, wa.z, acc[t][2]);
                acc[t][3] = fmaf(xv, wa.w, acc[t][3]);
                acc[t][4] = fmaf(xv, wb.x, acc[t][4]);
                acc[t][5] = fmaf(xv, wb.y, acc[t][5]);
                acc[t][6] = fmaf(xv, wb.z, acc[t][6]);
                acc[t][7] = fmaf(xv, wb.w, acc[t][7]);
            }
        }
        __syncthreads();   // wl reused next half
    }

    #pragma unroll
    for (int t = 0; t < TR; ++t) {
        const int gr = row0 + rg * TR + t;
        if (gr >= N_NODES) continue;
        float* yp = &Y[(size_t)gr * M];
        float4 o0 = {acc[t][0], acc[t][1], acc[t][2], acc[t][3]};
        float4 o1 = {acc[t][4], acc[t][5], acc[t][6], acc[t][7]};
        if (BIAS) {
            const float4 ba = *reinterpret_cast<const float4*>(&bias[c_lo]);
            const float4 bb = *reinterpret_cast<const float4*>(&bias[c_hi]);
            o0.x += ba.x; o0.y += ba.y; o0.z += ba.z; o0.w += ba.w;
            o1.x += bb.x; o1.y += bb.y; o1.z += bb.z; o1.w += bb.w;
        }
        *reinterpret_cast<float4*>(yp + c_lo) = o0;
        *reinterpret_cast<float4*>(yp + c_hi) = o1;
    }
}

// ---------------------------------------------------------------------------
// CSR build: histogram -> exclusive scan (Blelloch + redundant block-prefix)
// -> bucket fill. fill_k mutates rs in place; post-fill rs[n] == row_start[n+1].
// ---------------------------------------------------------------------------
__global__ __launch_bounds__(256) void hist_k(const int* __restrict__ dst_i,
                                              int* __restrict__ cnt) {
    const int stride = gridDim.x * blockDim.x;
    for (int e = blockIdx.x * blockDim.x + threadIdx.x; e < N_EDGES; e += stride)
        atomicAdd(&cnt[dst_i[e]], 1);
}

__global__ __launch_bounds__(1024) void scan1_k(const int* __restrict__ cnt,
                                                int* __restrict__ excl,
                                                int* __restrict__ bsum) {
    __shared__ int buf[SCAN_TILE];
    const int t = threadIdx.x;
    const int base = blockIdx.x * SCAN_TILE;
    buf[t] = (base + t < N_NODES) ? cnt[base + t] : 0;
    buf[t + 1024] = (base + t + 1024 < N_NODES) ? cnt[base + t + 1024] : 0;

    for (int d = 1; d < SCAN_TILE; d <<= 1) {
        __syncthreads();
        const int idx = (t + 1) * d * 2 - 1;
        if (idx < SCAN_TILE) buf[idx] += buf[idx - d];
    }
    __syncthreads();
    if (t == 0) {
        bsum[blockIdx.x] = buf[SCAN_TILE - 1];
        buf[SCAN_TILE - 1] = 0;
    }
    for (int d = SCAN_TILE / 2; d >= 1; d >>= 1) {
        __syncthreads();
        const int idx = (t + 1) * d * 2 - 1;
        if (idx < SCAN_TILE) {
            const int tmp = buf[idx - d];
            buf[idx - d] = buf[idx];
            buf[idx] += tmp;
        }
    }
    __syncthreads();
    if (base + t < N_NODES) excl[base + t] = buf[t];
    if (base + t + 1024 < N_NODES) excl[base + t + 1024] = buf[t + 1024];
}

// scan3: adds block-prefix of bsum to each element. Every block redundantly
// computes the 25-entry exclusive prefix in LDS (replaces the old scan2_k).
__global__ __launch_bounds__(256) void scan3_k(int* __restrict__ rs,
                                               const int* __restrict__ bsum) {
    __shared__ int pref[SCAN_NBLK];
    if (threadIdx.x == 0) {
        int acc = 0;
        #pragma unroll
        for (int b = 0; b < SCAN_NBLK; ++b) {
            pref[b] = acc;
            acc += bsum[b];
        }
    }
    __syncthreads();
    const int stride = gridDim.x * blockDim.x;
    for (int i = blockIdx.x * blockDim.x + threadIdx.x; i < N_NODES; i += stride)
        rs[i] += pref[i / SCAN_TILE];
}

// mutates rs in place: after this, rs[n] == original row_start[n+1]
__global__ __launch_bounds__(256) void fill_k(const int* __restrict__ dst_i,
                                              const int* __restrict__ src_i,
                                              int* __restrict__ rs,
                                              int* __restrict__ csr_src) {
    const int stride = gridDim.x * blockDim.x;
    for (int e = blockIdx.x * blockDim.x + threadIdx.x; e < N_EDGES; e += stride) {
        const int p = atomicAdd(&rs[dst_i[e]], 1);
        csr_src[p] = src_i[e];
    }
}

// ---------------------------------------------------------------------------
// Gather-aggregate: one wave per dst node. A[n][:] = sum_{j in csr[n]} S[j][:]
// beg/end from the shifted rs (see fill_k).
// ---------------------------------------------------------------------------
__global__ __launch_bounds__(256) void agg_k(const float* __restrict__ S,
                                             const int* __restrict__ rs,
                                             const int* __restrict__ csr_src,
                                             float* __restrict__ A) {
    const int wave = threadIdx.x >> 6;
    const int lane = threadIdx.x & 63;
    const int n = blockIdx.x * 4 + wave;
    if (n >= N_NODES) return;
    const int beg = n ? rs[n - 1] : 0;
    const int end = rs[n];
    const float2* S2 = reinterpret_cast<const float2*>(S);

    float2 a0 = {0.f, 0.f}, a1 = {0.f, 0.f}, a2 = {0.f, 0.f}, a3 = {0.f, 0.f};
    int j = beg;
    for (; j + 3 < end; j += 4) {
        const int s0 = csr_src[j];
        const int s1 = csr_src[j + 1];
        const int s2 = csr_src[j + 2];
        const int s3 = csr_src[j + 3];
        const float2 v0 = S2[(size_t)s0 * 64 + lane];
        const float2 v1 = S2[(size_t)s1 * 64 + lane];
        const float2 v2 = S2[(size_t)s2 * 64 + lane];
        const float2 v3 = S2[(size_t)s3 * 64 + lane];
        a0.x += v0.x; a0.y += v0.y;
        a1.x += v1.x; a1.y += v1.y;
        a2.x += v2.x; a2.y += v2.y;
        a3.x += v3.x; a3.y += v3.y;
    }
    for (; j < end; ++j) {
        const int s0 = csr_src[j];
        const float2 v0 = S2[(size_t)s0 * 64 + lane];
        a0.x += v0.x; a0.y += v0.y;
    }
    a0.x += a1.x + a2.x + a3.x;
    a0.y += a1.y + a2.y + a3.y;
    reinterpret_cast<float2*>(A)[(size_t)n * 64 + lane] = a0;
}

// ---------------------------------------------------------------------------
// Fallback (ws too small): atomic scatter
// ---------------------------------------------------------------------------
__global__ __launch_bounds__(256) void scatter_k(const float* __restrict__ S,
                                                 const int* __restrict__ dst_i,
                                                 const int* __restrict__ src_i,
                                                 float* __restrict__ A) {
    const long total = (long)N_EDGES * 32;
    const float4* S4 = reinterpret_cast<const float4*>(S);
    const long stride = (long)gridDim.x * blockDim.x;
    for (long i = (long)blockIdx.x * blockDim.x + threadIdx.x; i < total; i += stride) {
        const int e = (int)(i >> 5);
        const int c = (int)(i & 31);
        const int s = src_i[e];
        const int d = dst_i[e];
        const float4 v = S4[(size_t)s * 32 + c];
        float* p = &A[(size_t)d * 128 + (size_t)c * 4];
        atomicAdd(p + 0, v.x);
        atomicAdd(p + 1, v.y);
        atomicAdd(p + 2, v.z);
        atomicAdd(p + 3, v.w);
    }
}

extern "C" void kernel_launch(void* const* d_in, const int* in_sizes, int n_in,
                              void* d_out, int out_size, void* d_ws, size_t ws_size,
                              hipStream_t stream) {
    const int* edge = (const int*)d_in[0];   // [2][E]: row0=dst (segment ids), row1=src (gather ids)
    const float* feat = (const float*)d_in[1];
    const float* W0 = (const float*)d_in[2];
    const float* W1 = (const float*)d_in[3];
    const float* Wout = (const float*)d_in[4];
    const float* bout = (const float*)d_in[5];
    float* out = (float*)d_out;

    const int* dst_i = edge;
    const int* src_i = edge + N_EDGES;

    const size_t feat_elems = (size_t)N_NODES * 128;
    float* buf0 = (float*)d_ws;                 // support [N x 128]
    float* buf1 = buf0 + feat_elems;            // agg     [N x 128]

    char* p = (char*)(buf1 + feat_elems);
    int* rs = (int*)p;                          // N ints: scan out, fill-mutated
    p += (N_NODES + 1) * sizeof(int);
    int* cnt = (int*)p;                         // N ints: histogram
    p += N_NODES * sizeof(int);
    int* bsum = (int*)p;                        // SCAN_NBLK ints
    p += 32 * sizeof(int);
    int* csr_src = (int*)p;                     // E ints
    p += (size_t)N_EDGES * sizeof(int);
    const size_t needed = (size_t)((char*)p - (char*)d_ws);

    const int gemm_blocks = (N_NODES + 63) / 64;  // 782
    const int agg_blocks = (N_NODES + 3) / 4;     // 12500

    if (ws_size >= needed) {
        // ---- build CSR once (shared by both layers) ----
        hipMemsetAsync(cnt, 0, N_NODES * sizeof(int), stream);
        hist_k<<<1024, 256, 0, stream>>>(dst_i, cnt);
        scan1_k<<<SCAN_NBLK, 1024, 0, stream>>>(cnt, rs, bsum);
        scan3_k<<<128, 256, 0, stream>>>(rs, bsum);
        fill_k<<<1024, 256, 0, stream>>>(dst_i, src_i, rs, csr_src);

        // ---- layer 1 ----
        gemm_k<128, false, false><<<gemm_blocks, 512, 0, stream>>>(feat, W0, nullptr, buf0);
        agg_k<<<agg_blocks, 256, 0, stream>>>(buf0, rs, csr_src, buf1);
        // ---- layer 2 ----
        gemm_k<128, true, false><<<gemm_blocks, 512, 0, stream>>>(buf1, W1, nullptr, buf0);
        agg_k<<<agg_blocks, 256, 0, stream>>>(buf0, rs, csr_src, buf1);
        // ---- head ----
        gemm_k<64, true, true><<<gemm_blocks, 512, 0, stream>>>(buf1, Wout, bout, out);
    } else {
        // fallback: atomic path
        const size_t agg_bytes = feat_elems * sizeof(float);
        gemm_k<128, false, false><<<gemm_blocks, 512, 0, stream>>>(feat, W0, nullptr, buf0);
        hipMemsetAsync(buf1, 0, agg_bytes, stream);
        scatter_k<<<8192, 256, 0, stream>>>(buf0, dst_i, src_i, buf1);
        gemm_k<128, true, false><<<gemm_blocks, 512, 0, stream>>>(buf1, W1, nullptr, buf0);
        hipMemsetAsync(buf1, 0, agg_bytes, stream);
        scatter_k<<<8192, 256, 0, stream>>>(buf0, dst_i, src_i, buf1);
        gemm_k<64, true, true><<<gemm_blocks, 512, 0, stream>>>(buf1, Wout, bout, out);
    }
}

// Round 13
// 371.454 us; speedup vs baseline: 7.8016x; 1.0203x over previous
//
#include <hip/hip_runtime.h>

#define N_NODES 50000
#define N_EDGES 800000
#define SCAN_TILE 2048
#define SCAN_NBLK ((N_NODES + SCAN_TILE - 1) / SCAN_TILE)  // 25

// ---------------------------------------------------------------------------
// GEMM: Y[N x M] = (RELU_IN ? relu(X) : X)[N x 128] @ W[128 x M] (+ bias)
// Block: 64 rows x M cols, 512 threads.
// W staged in two K-halves (32KB max) -> LDS 66KB -> 2 blocks/CU.
// Column split c_lo/c_hi at 16B lane stride -> LDS reads <=2-way (free).
// ---------------------------------------------------------------------------
template <int M, bool RELU_IN, bool BIAS>
__global__ __launch_bounds__(512) void gemm_k(const float* __restrict__ X,
                                              const float* __restrict__ W,
                                              const float* __restrict__ bias,
                                              float* __restrict__ Y) {
    constexpr int K = 128;
    constexpr int KH = 64;          // K-half staged per pass
    constexpr int ROWS = 64;
    constexpr int XSTR = 136;

    __shared__ float wl[KH * M];    // 32KB for M=128, 16KB for M=64
    __shared__ float xl[ROWS * XSTR];

    const int tid = threadIdx.x;
    const int row0 = blockIdx.x * ROWS;

    // ---- stage X tile (64 rows x 128) via float4, fused ReLU ----
    {
        const float4* x4 = reinterpret_cast<const float4*>(X);
        #pragma unroll
        for (int i = tid; i < ROWS * 32; i += 512) {
            const int r = i >> 5, c = i & 31;
            const int gr = row0 + r;
            float4 v = {0.f, 0.f, 0.f, 0.f};
            if (gr < N_NODES) v = x4[(size_t)gr * 32 + c];
            if (RELU_IN) {
                v.x = fmaxf(v.x, 0.f);
                v.y = fmaxf(v.y, 0.f);
                v.z = fmaxf(v.z, 0.f);
                v.w = fmaxf(v.w, 0.f);
            }
            reinterpret_cast<float4*>(&xl[r * XSTR])[c] = v;
        }
    }

    constexpr int TPRG = M / 8;        // threads covering the col dim
    constexpr int NRG = 512 / TPRG;    // row-groups per block
    constexpr int TR = ROWS / NRG;     // rows per thread
    const int rg = tid / TPRG;
    const int cq = tid % TPRG;
    const int c_lo = cq * 4;
    const int c_hi = M / 2 + cq * 4;

    float acc[TR][8];
    #pragma unroll
    for (int t = 0; t < TR; ++t)
        #pragma unroll
        for (int j = 0; j < 8; ++j) acc[t][j] = 0.f;

    #pragma unroll
    for (int h = 0; h < K / KH; ++h) {
        // stage W rows [h*KH, h*KH+KH) -- consecutive float4s, conflict-free
        {
            const float4* w4 = reinterpret_cast<const float4*>(W + h * KH * M);
            float4* wl4 = reinterpret_cast<float4*>(wl);
            constexpr int TOT4 = KH * M / 4;
            #pragma unroll
            for (int i = tid; i < TOT4; i += 512) wl4[i] = w4[i];
        }
        __syncthreads();

        #pragma unroll 8
        for (int k = 0; k < KH; ++k) {
            const float4 wa = *reinterpret_cast<const float4*>(&wl[k * M + c_lo]);
            const float4 wb = *reinterpret_cast<const float4*>(&wl[k * M + c_hi]);
            const int gk = h * KH + k;
            #pragma unroll
            for (int t = 0; t < TR; ++t) {
                const float xv = xl[(rg * TR + t) * XSTR + gk];
                acc[t][0] = fmaf(xv, wa.x, acc[t][0]);
                acc[t][1] = fmaf(xv, wa.y, acc[t][1]);
                acc[t][2] = fmaf(xv, wa.z, acc[t][2]);
                acc[t][3] = fmaf(xv, wa.w, acc[t][3]);
                acc[t][4] = fmaf(xv, wb.x, acc[t][4]);
                acc[t][5] = fmaf(xv, wb.y, acc[t][5]);
                acc[t][6] = fmaf(xv, wb.z, acc[t][6]);
                acc[t][7] = fmaf(xv, wb.w, acc[t][7]);
            }
        }
        __syncthreads();   // wl reused next half
    }

    #pragma unroll
    for (int t = 0; t < TR; ++t) {
        const int gr = row0 + rg * TR + t;
        if (gr >= N_NODES) continue;
        float* yp = &Y[(size_t)gr * M];
        float4 o0 = {acc[t][0], acc[t][1], acc[t][2], acc[t][3]};
        float4 o1 = {acc[t][4], acc[t][5], acc[t][6], acc[t][7]};
        if (BIAS) {
            const float4 ba = *reinterpret_cast<const float4*>(&bias[c_lo]);
            const float4 bb = *reinterpret_cast<const float4*>(&bias[c_hi]);
            o0.x += ba.x; o0.y += ba.y; o0.z += ba.z; o0.w += ba.w;
            o1.x += bb.x; o1.y += bb.y; o1.z += bb.z; o1.w += bb.w;
        }
        *reinterpret_cast<float4*>(yp + c_lo) = o0;
        *reinterpret_cast<float4*>(yp + c_hi) = o1;
    }
}

// ---------------------------------------------------------------------------
// CSR build: histogram -> exclusive scan (Blelloch + redundant block-prefix)
// -> bucket fill. fill_k mutates rs in place; post-fill rs[n] == row_start[n+1].
// ---------------------------------------------------------------------------
__global__ __launch_bounds__(256) void hist_k(const int* __restrict__ dst_i,
                                              int* __restrict__ cnt) {
    const int stride = gridDim.x * blockDim.x;
    for (int e = blockIdx.x * blockDim.x + threadIdx.x; e < N_EDGES; e += stride)
        atomicAdd(&cnt[dst_i[e]], 1);
}

__global__ __launch_bounds__(1024) void scan1_k(const int* __restrict__ cnt,
                                                int* __restrict__ excl,
                                                int* __restrict__ bsum) {
    __shared__ int buf[SCAN_TILE];
    const int t = threadIdx.x;
    const int base = blockIdx.x * SCAN_TILE;
    buf[t] = (base + t < N_NODES) ? cnt[base + t] : 0;
    buf[t + 1024] = (base + t + 1024 < N_NODES) ? cnt[base + t + 1024] : 0;

    for (int d = 1; d < SCAN_TILE; d <<= 1) {
        __syncthreads();
        const int idx = (t + 1) * d * 2 - 1;
        if (idx < SCAN_TILE) buf[idx] += buf[idx - d];
    }
    __syncthreads();
    if (t == 0) {
        bsum[blockIdx.x] = buf[SCAN_TILE - 1];
        buf[SCAN_TILE - 1] = 0;
    }
    for (int d = SCAN_TILE / 2; d >= 1; d >>= 1) {
        __syncthreads();
        const int idx = (t + 1) * d * 2 - 1;
        if (idx < SCAN_TILE) {
            const int tmp = buf[idx - d];
            buf[idx - d] = buf[idx];
            buf[idx] += tmp;
        }
    }
    __syncthreads();
    if (base + t < N_NODES) excl[base + t] = buf[t];
    if (base + t + 1024 < N_NODES) excl[base + t + 1024] = buf[t + 1024];
}

// scan3: adds block-prefix of bsum to each element. Every block redundantly
// computes the 25-entry exclusive prefix in LDS (replaces the old scan2_k).
__global__ __launch_bounds__(256) void scan3_k(int* __restrict__ rs,
                                               const int* __restrict__ bsum) {
    __shared__ int pref[SCAN_NBLK];
    if (threadIdx.x == 0) {
        int acc = 0;
        #pragma unroll
        for (int b = 0; b < SCAN_NBLK; ++b) {
            pref[b] = acc;
            acc += bsum[b];
        }
    }
    __syncthreads();
    const int stride = gridDim.x * blockDim.x;
    for (int i = blockIdx.x * blockDim.x + threadIdx.x; i < N_NODES; i += stride)
        rs[i] += pref[i / SCAN_TILE];
}

// mutates rs in place: after this, rs[n] == original row_start[n+1]
__global__ __launch_bounds__(256) void fill_k(const int* __restrict__ dst_i,
                                              const int* __restrict__ src_i,
                                              int* __restrict__ rs,
                                              int* __restrict__ csr_src) {
    const int stride = gridDim.x * blockDim.x;
    for (int e = blockIdx.x * blockDim.x + threadIdx.x; e < N_EDGES; e += stride) {
        const int p = atomicAdd(&rs[dst_i[e]], 1);
        csr_src[p] = src_i[e];
    }
}

// ---------------------------------------------------------------------------
// Gather-aggregate: one wave per dst node, 2 edges per wave-iteration.
// Lanes 0-31 carry edge j, lanes 32-63 carry edge j+1; each lane holds a
// float4 (16B) column slice. 4 accumulator sets -> 8 rows (4KB) in flight.
// Cross-half __shfl_xor(32) combine at the end; lanes 0-31 store the row.
// ---------------------------------------------------------------------------
__global__ __launch_bounds__(256) void agg_k(const float* __restrict__ S,
                                             const int* __restrict__ rs,
                                             const int* __restrict__ csr_src,
                                             float* __restrict__ A) {
    const int wave = threadIdx.x >> 6;
    const int lane = threadIdx.x & 63;
    const int half = lane >> 5;      // 0: even-slot edge, 1: odd-slot edge
    const int l32 = lane & 31;       // float4 column slot within the row
    const int n = blockIdx.x * 4 + wave;
    if (n >= N_NODES) return;
    const int beg = n ? rs[n - 1] : 0;
    const int end = rs[n];
    const float4* S4 = reinterpret_cast<const float4*>(S);  // 32 float4 per row

    float4 a0 = {0.f, 0.f, 0.f, 0.f}, a1 = {0.f, 0.f, 0.f, 0.f};
    float4 a2 = {0.f, 0.f, 0.f, 0.f}, a3 = {0.f, 0.f, 0.f, 0.f};

    int j = beg;
    for (; j + 7 < end; j += 8) {   // 4 pairs = 8 edges in flight
        const int s0 = csr_src[j + half];
        const int s1 = csr_src[j + 2 + half];
        const int s2 = csr_src[j + 4 + half];
        const int s3 = csr_src[j + 6 + half];
        const float4 v0 = S4[(size_t)s0 * 32 + l32];
        const float4 v1 = S4[(size_t)s1 * 32 + l32];
        const float4 v2 = S4[(size_t)s2 * 32 + l32];
        const float4 v3 = S4[(size_t)s3 * 32 + l32];
        a0.x += v0.x; a0.y += v0.y; a0.z += v0.z; a0.w += v0.w;
        a1.x += v1.x; a1.y += v1.y; a1.z += v1.z; a1.w += v1.w;
        a2.x += v2.x; a2.y += v2.y; a2.z += v2.z; a2.w += v2.w;
        a3.x += v3.x; a3.y += v3.y; a3.z += v3.z; a3.w += v3.w;
    }
    for (; j + 1 < end; j += 2) {   // leftover pairs
        const int s0 = csr_src[j + half];
        const float4 v0 = S4[(size_t)s0 * 32 + l32];
        a0.x += v0.x; a0.y += v0.y; a0.z += v0.z; a0.w += v0.w;
    }
    if (j < end && half == 0) {     // single trailing edge: lower half only
        const int s0 = csr_src[j];
        const float4 v0 = S4[(size_t)s0 * 32 + l32];
        a0.x += v0.x; a0.y += v0.y; a0.z += v0.z; a0.w += v0.w;
    }

    a0.x += a1.x + a2.x + a3.x;
    a0.y += a1.y + a2.y + a3.y;
    a0.z += a1.z + a2.z + a3.z;
    a0.w += a1.w + a2.w + a3.w;

    // combine the two halves (lane ^ 32), then lanes 0-31 hold the full sum
    a0.x += __shfl_xor(a0.x, 32);
    a0.y += __shfl_xor(a0.y, 32);
    a0.z += __shfl_xor(a0.z, 32);
    a0.w += __shfl_xor(a0.w, 32);

    if (half == 0)
        reinterpret_cast<float4*>(A)[(size_t)n * 32 + l32] = a0;
}

// ---------------------------------------------------------------------------
// Fallback (ws too small): atomic scatter
// ---------------------------------------------------------------------------
__global__ __launch_bounds__(256) void scatter_k(const float* __restrict__ S,
                                                 const int* __restrict__ dst_i,
                                                 const int* __restrict__ src_i,
                                                 float* __restrict__ A) {
    const long total = (long)N_EDGES * 32;
    const float4* S4 = reinterpret_cast<const float4*>(S);
    const long stride = (long)gridDim.x * blockDim.x;
    for (long i = (long)blockIdx.x * blockDim.x + threadIdx.x; i < total; i += stride) {
        const int e = (int)(i >> 5);
        const int c = (int)(i & 31);
        const int s = src_i[e];
        const int d = dst_i[e];
        const float4 v = S4[(size_t)s * 32 + c];
        float* p = &A[(size_t)d * 128 + (size_t)c * 4];
        atomicAdd(p + 0, v.x);
        atomicAdd(p + 1, v.y);
        atomicAdd(p + 2, v.z);
        atomicAdd(p + 3, v.w);
    }
}

extern "C" void kernel_launch(void* const* d_in, const int* in_sizes, int n_in,
                              void* d_out, int out_size, void* d_ws, size_t ws_size,
                              hipStream_t stream) {
    const int* edge = (const int*)d_in[0];   // [2][E]: row0=dst (segment ids), row1=src (gather ids)
    const float* feat = (const float*)d_in[1];
    const float* W0 = (const float*)d_in[2];
    const float* W1 = (const float*)d_in[3];
    const float* Wout = (const float*)d_in[4];
    const float* bout = (const float*)d_in[5];
    float* out = (float*)d_out;

    const int* dst_i = edge;
    const int* src_i = edge + N_EDGES;

    const size_t feat_elems = (size_t)N_NODES * 128;
    float* buf0 = (float*)d_ws;                 // support [N x 128]
    float* buf1 = buf0 + feat_elems;            // agg     [N x 128]

    char* p = (char*)(buf1 + feat_elems);
    int* rs = (int*)p;                          // N ints: scan out, fill-mutated
    p += (N_NODES + 1) * sizeof(int);
    int* cnt = (int*)p;                         // N ints: histogram
    p += N_NODES * sizeof(int);
    int* bsum = (int*)p;                        // SCAN_NBLK ints
    p += 32 * sizeof(int);
    int* csr_src = (int*)p;                     // E ints
    p += (size_t)N_EDGES * sizeof(int);
    const size_t needed = (size_t)((char*)p - (char*)d_ws);

    const int gemm_blocks = (N_NODES + 63) / 64;  // 782
    const int agg_blocks = (N_NODES + 3) / 4;     // 12500

    if (ws_size >= needed) {
        // ---- build CSR once (shared by both layers) ----
        hipMemsetAsync(cnt, 0, N_NODES * sizeof(int), stream);
        hist_k<<<1024, 256, 0, stream>>>(dst_i, cnt);
        scan1_k<<<SCAN_NBLK, 1024, 0, stream>>>(cnt, rs, bsum);
        scan3_k<<<128, 256, 0, stream>>>(rs, bsum);
        fill_k<<<1024, 256, 0, stream>>>(dst_i, src_i, rs, csr_src);

        // ---- layer 1 ----
        gemm_k<128, false, false><<<gemm_blocks, 512, 0, stream>>>(feat, W0, nullptr, buf0);
        agg_k<<<agg_blocks, 256, 0, stream>>>(buf0, rs, csr_src, buf1);
        // ---- layer 2 ----
        gemm_k<128, true, false><<<gemm_blocks, 512, 0, stream>>>(buf1, W1, nullptr, buf0);
        agg_k<<<agg_blocks, 256, 0, stream>>>(buf0, rs, csr_src, buf1);
        // ---- head ----
        gemm_k<64, true, true><<<gemm_blocks, 512, 0, stream>>>(buf1, Wout, bout, out);
    } else {
        // fallback: atomic path
        const size_t agg_bytes = feat_elems * sizeof(float);
        gemm_k<128, false, false><<<gemm_blocks, 512, 0, stream>>>(feat, W0, nullptr, buf0);
        hipMemsetAsync(buf1, 0, agg_bytes, stream);
        scatter_k<<<8192, 256, 0, stream>>>(buf0, dst_i, src_i, buf1);
        gemm_k<128, true, false><<<gemm_blocks, 512, 0, stream>>>(buf1, W1, nullptr, buf0);
        hipMemsetAsync(buf1, 0, agg_bytes, stream);
        scatter_k<<<8192, 256, 0, stream>>>(buf0, dst_i, src_i, buf1);
        gemm_k<64, true, true><<<gemm_blocks, 512, 0, stream>>>(buf1, Wout, bout, out);
    }
}

// Round 15
// 333.181 us; speedup vs baseline: 8.6978x; 1.1149x over previous
//
#include <hip/hip_runtime.h>
#include <hip/hip_fp16.h>

#define N_NODES 50000
#define N_EDGES 800000
#define SCAN_TILE 2048
#define SCAN_NBLK ((N_NODES + SCAN_TILE - 1) / SCAN_TILE)  // 25

// ---------------------------------------------------------------------------
// GEMM: Y[N x M] = (RELU_IN ? relu(X) : X)[N x 128] @ W[128 x M] (+ bias)
// Block: 64 rows x M cols, 512 threads.
// W staged in two K-halves (32KB max) -> LDS 66KB -> 2 blocks/CU.
// Column split c_lo/c_hi at 16B lane stride -> LDS reads <=2-way (free).
// OUT_HALF: convert the output row to fp16 (gather-side traffic halving).
// ---------------------------------------------------------------------------
template <int M, bool RELU_IN, bool BIAS, bool OUT_HALF>
__global__ __launch_bounds__(512) void gemm_k(const float* __restrict__ X,
                                              const float* __restrict__ W,
                                              const float* __restrict__ bias,
                                              void* __restrict__ Yv) {
    constexpr int K = 128;
    constexpr int KH = 64;          // K-half staged per pass
    constexpr int ROWS = 64;
    constexpr int XSTR = 136;

    __shared__ float wl[KH * M];    // 32KB for M=128, 16KB for M=64
    __shared__ float xl[ROWS * XSTR];

    const int tid = threadIdx.x;
    const int row0 = blockIdx.x * ROWS;

    // ---- stage X tile (64 rows x 128) via float4, fused ReLU ----
    {
        const float4* x4 = reinterpret_cast<const float4*>(X);
        #pragma unroll
        for (int i = tid; i < ROWS * 32; i += 512) {
            const int r = i >> 5, c = i & 31;
            const int gr = row0 + r;
            float4 v = {0.f, 0.f, 0.f, 0.f};
            if (gr < N_NODES) v = x4[(size_t)gr * 32 + c];
            if (RELU_IN) {
                v.x = fmaxf(v.x, 0.f);
                v.y = fmaxf(v.y, 0.f);
                v.z = fmaxf(v.z, 0.f);
                v.w = fmaxf(v.w, 0.f);
            }
            reinterpret_cast<float4*>(&xl[r * XSTR])[c] = v;
        }
    }

    constexpr int TPRG = M / 8;        // threads covering the col dim
    constexpr int NRG = 512 / TPRG;    // row-groups per block
    constexpr int TR = ROWS / NRG;     // rows per thread
    const int rg = tid / TPRG;
    const int cq = tid % TPRG;
    const int c_lo = cq * 4;
    const int c_hi = M / 2 + cq * 4;

    float acc[TR][8];
    #pragma unroll
    for (int t = 0; t < TR; ++t)
        #pragma unroll
        for (int j = 0; j < 8; ++j) acc[t][j] = 0.f;

    #pragma unroll
    for (int h = 0; h < K / KH; ++h) {
        // stage W rows [h*KH, h*KH+KH) -- consecutive float4s, conflict-free
        {
            const float4* w4 = reinterpret_cast<const float4*>(W + h * KH * M);
            float4* wl4 = reinterpret_cast<float4*>(wl);
            constexpr int TOT4 = KH * M / 4;
            #pragma unroll
            for (int i = tid; i < TOT4; i += 512) wl4[i] = w4[i];
        }
        __syncthreads();

        #pragma unroll 8
        for (int k = 0; k < KH; ++k) {
            const float4 wa = *reinterpret_cast<const float4*>(&wl[k * M + c_lo]);
            const float4 wb = *reinterpret_cast<const float4*>(&wl[k * M + c_hi]);
            const int gk = h * KH + k;
            #pragma unroll
            for (int t = 0; t < TR; ++t) {
                const float xv = xl[(rg * TR + t) * XSTR + gk];
                acc[t][0] = fmaf(xv, wa.x, acc[t][0]);
                acc[t][1] = fmaf(xv, wa.y, acc[t][1]);
                acc[t][2] = fmaf(xv, wa.z, acc[t][2]);
                acc[t][3] = fmaf(xv, wa.w, acc[t][3]);
                acc[t][4] = fmaf(xv, wb.x, acc[t][4]);
                acc[t][5] = fmaf(xv, wb.y, acc[t][5]);
                acc[t][6] = fmaf(xv, wb.z, acc[t][6]);
                acc[t][7] = fmaf(xv, wb.w, acc[t][7]);
            }
        }
        __syncthreads();   // wl reused next half
    }

    #pragma unroll
    for (int t = 0; t < TR; ++t) {
        const int gr = row0 + rg * TR + t;
        if (gr >= N_NODES) continue;
        float4 o0 = {acc[t][0], acc[t][1], acc[t][2], acc[t][3]};
        float4 o1 = {acc[t][4], acc[t][5], acc[t][6], acc[t][7]};
        if (BIAS) {
            const float4 ba = *reinterpret_cast<const float4*>(&bias[c_lo]);
            const float4 bb = *reinterpret_cast<const float4*>(&bias[c_hi]);
            o0.x += ba.x; o0.y += ba.y; o0.z += ba.z; o0.w += ba.w;
            o1.x += bb.x; o1.y += bb.y; o1.z += bb.z; o1.w += bb.w;
        }
        if (OUT_HALF) {
            __half2* y2 = reinterpret_cast<__half2*>((__half*)Yv + (size_t)gr * M);
            y2[c_lo / 2]     = __floats2half2_rn(o0.x, o0.y);
            y2[c_lo / 2 + 1] = __floats2half2_rn(o0.z, o0.w);
            y2[c_hi / 2]     = __floats2half2_rn(o1.x, o1.y);
            y2[c_hi / 2 + 1] = __floats2half2_rn(o1.z, o1.w);
        } else {
            float* yp = (float*)Yv + (size_t)gr * M;
            *reinterpret_cast<float4*>(yp + c_lo) = o0;
            *reinterpret_cast<float4*>(yp + c_hi) = o1;
        }
    }
}

// ---------------------------------------------------------------------------
// CSR build: histogram -> exclusive scan (Blelloch + redundant block-prefix)
// -> bucket fill. fill_k mutates rs in place; post-fill rs[n] == row_start[n+1].
// ---------------------------------------------------------------------------
__global__ __launch_bounds__(256) void hist_k(const int* __restrict__ dst_i,
                                              int* __restrict__ cnt) {
    const int stride = gridDim.x * blockDim.x;
    for (int e = blockIdx.x * blockDim.x + threadIdx.x; e < N_EDGES; e += stride)
        atomicAdd(&cnt[dst_i[e]], 1);
}

__global__ __launch_bounds__(1024) void scan1_k(const int* __restrict__ cnt,
                                                int* __restrict__ excl,
                                                int* __restrict__ bsum) {
    __shared__ int buf[SCAN_TILE];
    const int t = threadIdx.x;
    const int base = blockIdx.x * SCAN_TILE;
    buf[t] = (base + t < N_NODES) ? cnt[base + t] : 0;
    buf[t + 1024] = (base + t + 1024 < N_NODES) ? cnt[base + t + 1024] : 0;

    for (int d = 1; d < SCAN_TILE; d <<= 1) {
        __syncthreads();
        const int idx = (t + 1) * d * 2 - 1;
        if (idx < SCAN_TILE) buf[idx] += buf[idx - d];
    }
    __syncthreads();
    if (t == 0) {
        bsum[blockIdx.x] = buf[SCAN_TILE - 1];
        buf[SCAN_TILE - 1] = 0;
    }
    for (int d = SCAN_TILE / 2; d >= 1; d >>= 1) {
        __syncthreads();
        const int idx = (t + 1) * d * 2 - 1;
        if (idx < SCAN_TILE) {
            const int tmp = buf[idx - d];
            buf[idx - d] = buf[idx];
            buf[idx] += tmp;
        }
    }
    __syncthreads();
    if (base + t < N_NODES) excl[base + t] = buf[t];
    if (base + t + 1024 < N_NODES) excl[base + t + 1024] = buf[t + 1024];
}

// scan3: adds block-prefix of bsum to each element. Every block redundantly
// computes the 25-entry exclusive prefix in LDS (replaces the old scan2_k).
__global__ __launch_bounds__(256) void scan3_k(int* __restrict__ rs,
                                               const int* __restrict__ bsum) {
    __shared__ int pref[SCAN_NBLK];
    if (threadIdx.x == 0) {
        int acc = 0;
        #pragma unroll
        for (int b = 0; b < SCAN_NBLK; ++b) {
            pref[b] = acc;
            acc += bsum[b];
        }
    }
    __syncthreads();
    const int stride = gridDim.x * blockDim.x;
    for (int i = blockIdx.x * blockDim.x + threadIdx.x; i < N_NODES; i += stride)
        rs[i] += pref[i / SCAN_TILE];
}

// mutates rs in place: after this, rs[n] == original row_start[n+1]
__global__ __launch_bounds__(256) void fill_k(const int* __restrict__ dst_i,
                                              const int* __restrict__ src_i,
                                              int* __restrict__ rs,
                                              int* __restrict__ csr_src) {
    const int stride = gridDim.x * blockDim.x;
    for (int e = blockIdx.x * blockDim.x + threadIdx.x; e < N_EDGES; e += stride) {
        const int p = atomicAdd(&rs[dst_i[e]], 1);
        csr_src[p] = src_i[e];
    }
}

// ---------------------------------------------------------------------------
// Gather-aggregate (fp16 source): one wave per dst node, 2 edges per
// wave-iteration. Lanes 0-31 carry edge j, lanes 32-63 edge j+1; each lane
// reads one uint2 (4 halfs, 8B) of the 256B row -> columns [4*l32,4*l32+4).
// fp32 accumulate; cross-half __shfl_xor(32); lanes 0-31 store float4.
// ---------------------------------------------------------------------------
__global__ __launch_bounds__(256) void agg_k(const __half* __restrict__ S,
                                             const int* __restrict__ rs,
                                             const int* __restrict__ csr_src,
                                             float* __restrict__ A) {
    const int wave = threadIdx.x >> 6;
    const int lane = threadIdx.x & 63;
    const int half_id = lane >> 5;   // 0: even-slot edge, 1: odd-slot edge
    const int l32 = lane & 31;       // 8B column slot within the row
    const int n = blockIdx.x * 4 + wave;
    if (n >= N_NODES) return;
    const int beg = n ? rs[n - 1] : 0;
    const int end = rs[n];
    const uint2* Sp = reinterpret_cast<const uint2*>(S);  // 32 uint2 per row

    float4 a0 = {0.f, 0.f, 0.f, 0.f}, a1 = {0.f, 0.f, 0.f, 0.f};
    float4 a2 = {0.f, 0.f, 0.f, 0.f}, a3 = {0.f, 0.f, 0.f, 0.f};

    auto acc4 = [&](float4& a, uint2 raw) {
        const __half2 h0 = *reinterpret_cast<const __half2*>(&raw.x);
        const __half2 h1 = *reinterpret_cast<const __half2*>(&raw.y);
        const float2 f0 = __half22float2(h0);
        const float2 f1 = __half22float2(h1);
        a.x += f0.x; a.y += f0.y; a.z += f1.x; a.w += f1.y;
    };

    int j = beg;
    for (; j + 7 < end; j += 8) {   // 4 pairs = 8 edges in flight
        const int s0 = csr_src[j + half_id];
        const int s1 = csr_src[j + 2 + half_id];
        const int s2 = csr_src[j + 4 + half_id];
        const int s3 = csr_src[j + 6 + half_id];
        const uint2 v0 = Sp[(size_t)s0 * 32 + l32];
        const uint2 v1 = Sp[(size_t)s1 * 32 + l32];
        const uint2 v2 = Sp[(size_t)s2 * 32 + l32];
        const uint2 v3 = Sp[(size_t)s3 * 32 + l32];
        acc4(a0, v0);
        acc4(a1, v1);
        acc4(a2, v2);
        acc4(a3, v3);
    }
    for (; j + 1 < end; j += 2) {   // leftover pairs
        const int s0 = csr_src[j + half_id];
        acc4(a0, Sp[(size_t)s0 * 32 + l32]);
    }
    if (j < end && half_id == 0) {  // single trailing edge: lower half only
        const int s0 = csr_src[j];
        acc4(a0, Sp[(size_t)s0 * 32 + l32]);
    }

    a0.x += a1.x + a2.x + a3.x;
    a0.y += a1.y + a2.y + a3.y;
    a0.z += a1.z + a2.z + a3.z;
    a0.w += a1.w + a2.w + a3.w;

    // combine the two halves (lane ^ 32), then lanes 0-31 hold the full sum
    a0.x += __shfl_xor(a0.x, 32);
    a0.y += __shfl_xor(a0.y, 32);
    a0.z += __shfl_xor(a0.z, 32);
    a0.w += __shfl_xor(a0.w, 32);

    if (half_id == 0)
        reinterpret_cast<float4*>(A)[(size_t)n * 32 + l32] = a0;
}

// ---------------------------------------------------------------------------
// Fallback (ws too small): atomic scatter, all-fp32 (own ws layout)
// ---------------------------------------------------------------------------
__global__ __launch_bounds__(256) void scatter_k(const float* __restrict__ S,
                                                 const int* __restrict__ dst_i,
                                                 const int* __restrict__ src_i,
                                                 float* __restrict__ A) {
    const long total = (long)N_EDGES * 32;
    const float4* S4 = reinterpret_cast<const float4*>(S);
    const long stride = (long)gridDim.x * blockDim.x;
    for (long i = (long)blockIdx.x * blockDim.x + threadIdx.x; i < total; i += stride) {
        const int e = (int)(i >> 5);
        const int c = (int)(i & 31);
        const int s = src_i[e];
        const int d = dst_i[e];
        const float4 v = S4[(size_t)s * 32 + c];
        float* p = &A[(size_t)d * 128 + (size_t)c * 4];
        atomicAdd(p + 0, v.x);
        atomicAdd(p + 1, v.y);
        atomicAdd(p + 2, v.z);
        atomicAdd(p + 3, v.w);
    }
}

extern "C" void kernel_launch(void* const* d_in, const int* in_sizes, int n_in,
                              void* d_out, int out_size, void* d_ws, size_t ws_size,
                              hipStream_t stream) {
    const int* edge = (const int*)d_in[0];   // [2][E]: row0=dst (segment ids), row1=src (gather ids)
    const float* feat = (const float*)d_in[1];
    const float* W0 = (const float*)d_in[2];
    const float* W1 = (const float*)d_in[3];
    const float* Wout = (const float*)d_in[4];
    const float* bout = (const float*)d_in[5];
    float* out = (float*)d_out;

    const int* dst_i = edge;
    const int* src_i = edge + N_EDGES;

    const size_t feat_elems = (size_t)N_NODES * 128;

    // main-path layout: fp32 agg | fp16 support | CSR ints
    float* aggf = (float*)d_ws;                    // [N*128] fp32
    __half* sup = (__half*)(aggf + feat_elems);    // [N*128] fp16
    char* p = (char*)(sup + feat_elems);
    int* rs = (int*)p;                             // N ints: scan out, fill-mutated
    p += (N_NODES + 1) * sizeof(int);
    int* cnt = (int*)p;                            // N ints: histogram
    p += N_NODES * sizeof(int);
    int* bsum = (int*)p;                           // SCAN_NBLK ints
    p += 32 * sizeof(int);
    int* csr_src = (int*)p;                        // E ints
    p += (size_t)N_EDGES * sizeof(int);
    const size_t needed = (size_t)((char*)p - (char*)d_ws);

    const int gemm_blocks = (N_NODES + 63) / 64;  // 782
    const int agg_blocks = (N_NODES + 3) / 4;     // 12500

    if (ws_size >= needed) {
        // ---- build CSR once (shared by both layers) ----
        hipMemsetAsync(cnt, 0, N_NODES * sizeof(int), stream);
        hist_k<<<1024, 256, 0, stream>>>(dst_i, cnt);
        scan1_k<<<SCAN_NBLK, 1024, 0, stream>>>(cnt, rs, bsum);
        scan3_k<<<128, 256, 0, stream>>>(rs, bsum);
        fill_k<<<1024, 256, 0, stream>>>(dst_i, src_i, rs, csr_src);

        // ---- layer 1: support(fp16) = feat @ W0 ; agg1(fp32) = A @ support ----
        gemm_k<128, false, false, true><<<gemm_blocks, 512, 0, stream>>>(feat, W0, nullptr, sup);
        agg_k<<<agg_blocks, 256, 0, stream>>>(sup, rs, csr_src, aggf);
        // ---- layer 2: support2(fp16) = relu(agg1) @ W1 ; agg2(fp32) = A @ support2 ----
        gemm_k<128, true, false, true><<<gemm_blocks, 512, 0, stream>>>(aggf, W1, nullptr, sup);
        agg_k<<<agg_blocks, 256, 0, stream>>>(sup, rs, csr_src, aggf);
        // ---- head: out = relu(agg2) @ W_out + b_out ----
        gemm_k<64, true, true, false><<<gemm_blocks, 512, 0, stream>>>(aggf, Wout, bout, out);
    } else {
        // fallback: all-fp32 atomic path (own layout: two fp32 buffers)
        float* buf0 = (float*)d_ws;
        float* buf1 = buf0 + feat_elems;
        const size_t agg_bytes = feat_elems * sizeof(float);
        gemm_k<128, false, false, false><<<gemm_blocks, 512, 0, stream>>>(feat, W0, nullptr, buf0);
        hipMemsetAsync(buf1, 0, agg_bytes, stream);
        scatter_k<<<8192, 256, 0, stream>>>(buf0, dst_i, src_i, buf1);
        gemm_k<128, true, false, false><<<gemm_blocks, 512, 0, stream>>>(buf1, W1, nullptr, buf0);
        hipMemsetAsync(buf1, 0, agg_bytes, stream);
        scatter_k<<<8192, 256, 0, stream>>>(buf0, dst_i, src_i, buf1);
        gemm_k<64, true, true, false><<<gemm_blocks, 512, 0, stream>>>(buf1, Wout, bout, out);
    }
}